// Round 14
// baseline (119.085 us; speedup 1.0000x reference)
//
#include <hip/hip_runtime.h>

// StrictOrthogonal: Q = orth(X) for X complex 16384x32 (stored (M,32,2) f32).
// Cholesky-QR == reference MGS to ~1e-6 (threshold 5.15e-4):
//   G = X^H X ; G = L~ D L~^H (unnormalized cols) ; Q = X L^{-H} per-row solve.
//
// R13 -> R14: COLD-I$ FIX. Evidence: gram (2KB loop code) runs at issue
// speed; every big-unrolled phase-C (R5..R13, 25-50KB straight-line) costs
// ~15-20us over its issue arithmetic; R11 falsified capacity (24KB no better
// than 50KB) -> the cost is cold STREAMING of the body, once per CU per
// launch, unhidden at 1 wave. This round keeps R10's exact structure/math
// and shrinks K2 code ~50KB -> ~15KB: outer chol/solve loops become RUNTIME
// loops in 4 compile-time chunks of 8 (clang loop unroll(disable));
// rdlane takes the runtime k (SGPR lane form); a[k]/xr[jj] extraction = 8-way
// uniform select; inner i unrolled from chunk base with wave-uniform i>k
// guards (<=1.25x triangle issue). Values per step identical to R10 ->
// absmax must stay 6.103516e-05.

__device__ __forceinline__ float rdlane(float v, int lane) {
  return __builtin_bit_cast(
      float, __builtin_amdgcn_readlane(__builtin_bit_cast(int, v), lane));
}

// ---------------------------------------------------------------- gram ----
// 256 blocks x 256 threads, 64 rows each (unchanged since R2; passed 10x).
__global__ __launch_bounds__(256) void gram_partial(const float* __restrict__ x,
                                                    float* __restrict__ G8) {
  __shared__ float lds[64 * 64];  // 64 rows x 32 complex = 16 KB
  const int t = threadIdx.x;
  const int j = t & 31, g = t >> 5;
  const size_t row0 = (size_t)blockIdx.x * 64;
  float ar[4] = {0.f, 0.f, 0.f, 0.f};
  float ai[4] = {0.f, 0.f, 0.f, 0.f};
  const float4* src = (const float4*)(x + row0 * 64);
  float4* dst = (float4*)lds;
#pragma unroll
  for (int q = 0; q < 4; ++q) dst[t + 256 * q] = src[t + 256 * q];
  __syncthreads();
#pragma unroll 4
  for (int m = 0; m < 64; ++m) {
    const float2* row = (const float2*)(lds + m * 64);
    const float2 xj = row[j];  // 2-way bank alias: free
#pragma unroll
    for (int q = 0; q < 4; ++q) {
      const float2 xi = row[g + q * 8];  // broadcast within 32-lane group
      ar[q] += xi.x * xj.x + xi.y * xj.y;  // conj(xi)*xj
      ai[q] += xi.x * xj.y - xi.y * xj.x;
    }
  }
  float* P = G8 + (size_t)(blockIdx.x & 7) * 2048;
#pragma unroll
  for (int q = 0; q < 4; ++q) {
    const int i = g + q * 8;
    atomicAdd(&P[(i * 32 + j) * 2 + 0], ar[q]);
    atomicAdd(&P[(i * 32 + j) * 2 + 1], ai[q]);
  }
}

// ----------------------------------------------------------- chol_solve ----
// R10's exact shape: 256 blocks x 64 threads (1 wave), 64 rows/block.
// Same phases, same per-step values; outer loops compacted (code ~15KB).
__global__ __launch_bounds__(64, 1) void chol_solve(const float* __restrict__ x,
                                                    const float* __restrict__ G8,
                                                    float* __restrict__ out) {
  __shared__ float4 xsp[64 * 17];  // 64 rows x 16 f4, row stride 17
  __shared__ float4 Gl[512];       // summed G, row-major complex
  __shared__ float2 Acm[33 * 32];  // L~ column-major, col stride 33
  const int t = threadIdx.x;
  const int j = t & 31;

  // ---- stage x coalesced (compact loop) ----
  const float4* src = (const float4*)(x + (size_t)blockIdx.x * 4096);
#pragma clang loop unroll(disable)
  for (int s = 0; s < 16; ++s) {
    const int gi = t + 64 * s;
    xsp[(gi >> 4) * 17 + (gi & 15)] = src[gi];
  }
  // ---- sum the 8 G copies (compact loops) ----
  {
    const float4* G8f4 = (const float4*)G8;
#pragma clang loop unroll(disable)
    for (int e = t; e < 512; e += 64) {
      float4 acc = G8f4[e];
#pragma clang loop unroll(disable)
      for (int c = 1; c < 8; ++c) {
        const float4 p = G8f4[c * 512 + e];
        acc.x += p.x; acc.y += p.y; acc.z += p.z; acc.w += p.w;
      }
      Gl[e] = acc;
    }
  }
  __syncthreads();  // single wave: cheap; orders LDS writes vs reads

  // ---- gather column j into registers ----
  float2 a[32];
#pragma unroll
  for (int i = 0; i < 32; ++i) a[i] = ((const float2*)Gl)[i * 32 + j];

  // ---- register Cholesky: 4 compile-time chunks x 8 runtime steps ----
#pragma unroll
  for (int kb = 0; kb < 32; kb += 8) {
    const int kkmax = (kb == 24) ? 7 : 8;  // k = 0..30
#pragma clang loop unroll(disable)
    for (int kk = 0; kk < kkmax; ++kk) {
      const int k = kb + kk;
      // extract v = a[k] (8-way uniform select within the chunk)
      float2 v = a[kb];
#pragma unroll
      for (int s = 1; s < 8; ++s)
        if (kk == s) v = a[kb + s];
      const float d = rdlane(v.x, k);  // runtime lane: v_readlane sgpr form
      const float invd = 1.0f / d;
      const bool act = (j > k);
      const float ux = act ? v.x * invd : 0.0f;  // v = A[k][j] for this lane
      const float uy = act ? v.y * invd : 0.0f;
#pragma unroll
      for (int i = kb + 1; i < 32; ++i) {
        if (i > k) {  // wave-uniform guard: skip or cndmask, value-exact
          const float cr = rdlane(a[i].x, k);  // A[i][k] from lane k
          const float ci = rdlane(a[i].y, k);
          a[i].x -= cr * ux - ci * uy;
          a[i].y -= cr * uy + ci * ux;
        }
      }
    }
  }
  // dump L~ column j; a[] dies here (no co-live pressure with xr)
  if (t < 32) {
#pragma unroll
    for (int i = 0; i < 32; ++i) Acm[j * 33 + i] = a[i];
  }
  __syncthreads();

  // ---- per-row forward solve: xr[] in regs, L~ via LDS broadcasts ----
  float2 xr[32];
#pragma unroll
  for (int q = 0; q < 16; ++q) {
    const float4 v = xsp[t * 17 + q];
    xr[2 * q].x = v.x; xr[2 * q].y = v.y;
    xr[2 * q + 1].x = v.z; xr[2 * q + 1].y = v.w;
  }
#pragma unroll
  for (int jb = 0; jb < 32; jb += 8) {
#pragma clang loop unroll(disable)
    for (int kk = 0; kk < 8; ++kk) {
      const int jj = jb + kk;
      // extract xr[jj] (8-way uniform select)
      float2 uraw = xr[jb];
#pragma unroll
      for (int s = 1; s < 8; ++s)
        if (kk == s) uraw = xr[jb + s];
      const float d = Acm[jj * 33 + jj].x;  // wave-uniform broadcast
      const float invd = 1.0f / d;
      const float invs = 1.0f / sqrtf(d);
      const float ux = uraw.x * invd, uy = uraw.y * invd;
      const float2 q2 = {uraw.x * invs, uraw.y * invs};
#pragma unroll
      for (int i = jb; i < 32; ++i) {
        if (i == jj) {  // wave-uniform
          xr[i] = q2;
        } else if (i > jj) {  // wave-uniform
          const float2 l = Acm[jj * 33 + i];  // read-only broadcast
          xr[i].x -= ux * l.x + uy * l.y;  // xr[i] -= u * conj(l)
          xr[i].y -= uy * l.x - ux * l.y;
        }
      }
    }
  }

  // ---- regs -> padded LDS -> coalesced f4 store ----
#pragma unroll
  for (int q = 0; q < 16; ++q) {
    float4 v;
    v.x = xr[2 * q].x; v.y = xr[2 * q].y;
    v.z = xr[2 * q + 1].x; v.w = xr[2 * q + 1].y;
    xsp[t * 17 + q] = v;
  }
  __syncthreads();
  float4* op = (float4*)(out + (size_t)blockIdx.x * 4096);
#pragma clang loop unroll(disable)
  for (int s = 0; s < 16; ++s) {
    const int gi = t + 64 * s;
    op[gi] = xsp[(gi >> 4) * 17 + (gi & 15)];
  }
}

// -------------------------------------------------------------- launch ----
extern "C" void kernel_launch(void* const* d_in, const int* in_sizes, int n_in,
                              void* d_out, int out_size, void* d_ws, size_t ws_size,
                              hipStream_t stream) {
  const float* x = (const float*)d_in[0];
  float* out = (float*)d_out;
  float* G8 = (float*)d_ws;  // 8 copies x 2048 floats = 64 KB (0xAA-poisoned)

  gram_partial<<<256, 256, 0, stream>>>(x, G8);
  chol_solve<<<256, 64, 0, stream>>>(x, G8, out);
}

// Round 15
// 107.154 us; speedup vs baseline: 1.1113x; 1.1113x over previous
//
#include <hip/hip_runtime.h>

// StrictOrthogonal: Q = orth(X) for X complex 16384x32 (stored (M,32,2) f32).
// Cholesky-QR == reference MGS to ~1e-6 (threshold 5.15e-4):
//   G = X^H X ; G = L~ D L~^H ; W = R^{-1} ; Q = X W.
//
// R14 -> R15: CODE OFF THE MANY-CU PATH. Session model (fits R10..R14):
// K2 cost = ~4us issue + ~0.45us/KB of unrolled code (cold I$ stream per CU,
// unhidden at 1 wave); register-array indices must be compile-time (R14's
// runtime-k rewrite tripled dynamic work -> 60.9us). So the 44KB of
// unavoidably-unrolled serial code (chol + winv) runs on ONE block only
// (<<<1,128>>>, 2 waves interleave the stream); the 256-CU kernels are tiny
// runtime-loop code: gram (2KB, proven) and apply (2KB, R2-proven dense
// matmul vs W). winv = R10's proven solve recurrence applied to e_c (lane c
// -> row c of W). All pieces from previously-passing rounds.

__device__ __forceinline__ float rdlane(float v, int lane) {
  return __builtin_bit_cast(
      float, __builtin_amdgcn_readlane(__builtin_bit_cast(int, v), lane));
}

// ---------------------------------------------------------------- gram ----
// 256 blocks x 256 threads, 64 rows each (unchanged since R2; passed 11x).
__global__ __launch_bounds__(256) void gram_partial(const float* __restrict__ x,
                                                    float* __restrict__ G8) {
  __shared__ float lds[64 * 64];  // 64 rows x 32 complex = 16 KB
  const int t = threadIdx.x;
  const int j = t & 31, g = t >> 5;
  const size_t row0 = (size_t)blockIdx.x * 64;
  float ar[4] = {0.f, 0.f, 0.f, 0.f};
  float ai[4] = {0.f, 0.f, 0.f, 0.f};
  const float4* src = (const float4*)(x + row0 * 64);
  float4* dst = (float4*)lds;
#pragma unroll
  for (int q = 0; q < 4; ++q) dst[t + 256 * q] = src[t + 256 * q];
  __syncthreads();
#pragma unroll 4
  for (int m = 0; m < 64; ++m) {
    const float2* row = (const float2*)(lds + m * 64);
    const float2 xj = row[j];  // 2-way bank alias: free
#pragma unroll
    for (int q = 0; q < 4; ++q) {
      const float2 xi = row[g + q * 8];  // broadcast within 32-lane group
      ar[q] += xi.x * xj.x + xi.y * xj.y;  // conj(xi)*xj
      ai[q] += xi.x * xj.y - xi.y * xj.x;
    }
  }
  float* P = G8 + (size_t)(blockIdx.x & 7) * 2048;
#pragma unroll
  for (int q = 0; q < 4; ++q) {
    const int i = g + q * 8;
    atomicAdd(&P[(i * 32 + j) * 2 + 0], ar[q]);
    atomicAdd(&P[(i * 32 + j) * 2 + 1], ai[q]);
  }
}

// ------------------------------------------------------------ chol_winv ----
// ONE block x 128 threads (2 waves walking the same code: the second wave
// hits I$ lines fetched by the first). Lane j = t&31 (upper lanes mirror).
//  gsum: a[i] = sum_c G8copy[c][i][j] straight into registers (R13, passed).
//  chol: register readlane cholesky (R13, passed); dump L~ col j -> Acm.
//  winv: R10's solve recurrence with xr = e_c  ==> xr becomes row c of
//        W = R^{-1} (steps jj<c are exact no-ops on zeros).
//  out:  lane c (t<32) writes W row c, row-major complex, to ws.
__global__ __launch_bounds__(128, 1) void chol_winv(const float* __restrict__ G8,
                                                    float* __restrict__ Wg) {
  __shared__ float2 Acm[33 * 32];  // L~ column-major, col stride 33
  const int t = threadIdx.x;
  const int j = t & 31;

  // ---- G8 sum straight into registers + register Cholesky ----
  {
    const float2* Gf2 = (const float2*)G8;
    float2 a[32];
#pragma unroll
    for (int i = 0; i < 32; ++i) {
      float2 s = Gf2[i * 32 + j];
#pragma unroll
      for (int c = 1; c < 8; ++c) {
        const float2 p = Gf2[c * 1024 + i * 32 + j];
        s.x += p.x;
        s.y += p.y;
      }
      a[i] = s;
    }
#pragma unroll
    for (int k = 0; k < 31; ++k) {
      const float invd = 1.0f / rdlane(a[k].x, k);
      const bool act = (j > k);
      const float ux = act ? a[k].x * invd : 0.0f;
      const float uy = act ? a[k].y * invd : 0.0f;
#pragma unroll
      for (int i = k + 1; i < 32; ++i) {
        const float cr = rdlane(a[i].x, k);  // A[i][k] from lane k
        const float ci = rdlane(a[i].y, k);
        a[i].x -= cr * ux - ci * uy;
        a[i].y -= cr * uy + ci * ux;
      }
    }
    if (t < 32) {  // dump L~ column j; a[] dies here
#pragma unroll
      for (int i = 0; i < 32; ++i) Acm[j * 33 + i] = a[i];
    }
  }
  __syncthreads();  // 2 waves: order Acm writes vs reads

  // ---- winv: solve recurrence on e_c -> row c of W (R10 math, passed) ----
  const int c = j;
  float2 xr[32];
#pragma unroll
  for (int i = 0; i < 32; ++i) {
    xr[i].x = (i == c) ? 1.0f : 0.0f;
    xr[i].y = 0.0f;
  }
#pragma unroll
  for (int jj = 0; jj < 32; ++jj) {
    const float d = Acm[jj * 33 + jj].x;  // wave-uniform broadcast
    const float invd = 1.0f / d;
    const float invs = 1.0f / sqrtf(d);
    const float ux = xr[jj].x * invd, uy = xr[jj].y * invd;
    xr[jj].x *= invs;
    xr[jj].y *= invs;
#pragma unroll
    for (int i = jj + 1; i < 32; ++i) {
      const float2 l = Acm[jj * 33 + i];  // read-only broadcast
      xr[i].x -= ux * l.x + uy * l.y;  // xr[i] -= u * conj(l)
      xr[i].y -= uy * l.x - ux * l.y;
    }
  }
  // ---- write W row c (row-major complex: Wg[(c*32+j)*2]) ----
  if (t < 32) {
    float2* Wr = (float2*)Wg + c * 32;
#pragma unroll
    for (int i = 0; i < 32; ++i) Wr[i] = xr[i];
  }
}

// --------------------------------------------------------------- apply ----
// Q = X W (R2 verbatim, passed). 1024 blocks x 256 threads, 16 rows/block;
// thread (mloc = t>>4, jp = t&15) computes complex pair (2jp, 2jp+1).
__global__ __launch_bounds__(256) void apply_qr(const float* __restrict__ x,
                                                const float* __restrict__ W,
                                                float* __restrict__ out) {
  __shared__ float w[2048];   // full 32x32 complex W
  __shared__ float xs[1024];  // 16 rows x 32 complex
  const int t = threadIdx.x;
  ((float4*)w)[t] = ((const float4*)W)[t];
  ((float4*)w)[t + 256] = ((const float4*)W)[t + 256];
  const size_t m0 = (size_t)blockIdx.x * 16;
  ((float4*)xs)[t] = ((const float4*)(x + m0 * 64))[t];
  __syncthreads();
  const int mloc = t >> 4, jp = t & 15;
  const float2* xrow = (const float2*)(xs + mloc * 64);
  float2 a0 = {0.f, 0.f}, a1 = {0.f, 0.f};
#pragma unroll
  for (int i = 0; i < 32; ++i) {
    const float2 xi = xrow[i];
    const float4 wv = ((const float4*)(w + i * 64))[jp];  // W[i][2jp..2jp+1]
    a0.x += xi.x * wv.x - xi.y * wv.y;
    a0.y += xi.x * wv.y + xi.y * wv.x;
    a1.x += xi.x * wv.z - xi.y * wv.w;
    a1.y += xi.x * wv.w + xi.y * wv.z;
  }
  float4 o;
  o.x = a0.x; o.y = a0.y; o.z = a1.x; o.w = a1.y;
  ((float4*)out)[(size_t)blockIdx.x * 256 + t] = o;
}

// -------------------------------------------------------------- launch ----
extern "C" void kernel_launch(void* const* d_in, const int* in_sizes, int n_in,
                              void* d_out, int out_size, void* d_ws, size_t ws_size,
                              hipStream_t stream) {
  const float* x = (const float*)d_in[0];
  float* out = (float*)d_out;
  float* G8 = (float*)d_ws;           // 8 copies x 2048 floats (0xAA-poisoned)
  float* Wg = (float*)d_ws + 16384;   // 2048 floats (W row-major complex)

  gram_partial<<<256, 256, 0, stream>>>(x, G8);
  chol_winv<<<1, 128, 0, stream>>>(G8, Wg);
  apply_qr<<<1024, 256, 0, stream>>>(x, Wg, out);
}